// Round 6
// baseline (882.430 us; speedup 1.0000x reference)
//
#include <hip/hip_runtime.h>
#include <math.h>

// Problem constants
#define S       2048
#define D       2048
#define EQ      2048   // N_Q_HEADS * HEAD_DIM
#define EK      512    // N_KV_HEADS * HEAD_DIM
#define ETOT    2560   // EQ + EK
#define NH      32
#define NKV     8
#define HD      64
#define KLEN    1024   // max(S*0.5, 2)

// Workspace layout (byte offsets)
#define OFF_COS   ((size_t)0)                    // [S][32] f32 = 256KB
#define OFF_SIN   ((size_t)(256u << 10))         // 256KB
#define OFF_QK    ((size_t)(1u << 20))           // [S][ETOT] f32 = 20MB
#define OFF_KT    ((size_t)(22u << 20))          // [NKV][64][S] f32 = 4MB
#define OFF_PART  ((size_t)(26u << 20))          // [1024][S] f32 = 8MB
#define OFF_VALS  ((size_t)(34u << 20))          // [S] f64 = 16KB
#define OFF_FLAGS ((size_t)((34u << 20) + (16u << 10)))   // [S] i32 = 8KB
#define OFF_ACCP  ((size_t)((34u << 20) + (32u << 10)))   // [32][S] f64 = 512KB

// ---------------------------------------------------------------------------
// 1) cos/sin tables in fp64 (fp32 arg reduction at pos~2047 gives ~1e-4 error,
//    j-correlated -> would destabilize the topk boundary).
__global__ void trig_kernel(float* __restrict__ cosT, float* __restrict__ sinT) {
  int idx = blockIdx.x * blockDim.x + threadIdx.x;  // S*32 = 65536
  int s = idx >> 5, i = idx & 31;
  double invf = 1.0 / pow(10000.0, (double)i / 32.0);
  double ang = (double)s * invf;
  cosT[idx] = (float)cos(ang);
  sinT[idx] = (float)sin(ang);
}

// ---------------------------------------------------------------------------
// 2) Fused gather + projection GEMM: C[s][e] = sum_d embed[ids[s]][d]*W[e][d].
//    R2's winning shape (256 thr, 64x64 tile, BK=16, 4x4 micro, 5120 waves)
//    minus its measured overheads:
//      - A staged in native [m][k] layout (pad to 20 fl): global float4 ==
//        LDS row, ONE ds_write_b128 (was 8 scalar writes -> the 1.05e7
//        conflicts). A-reads: per-4kk register-cached b128 along k; bases
//        m*80B alternate two banksets -> 2-way = free.
//      - double-buffered LDS: ONE barrier/iter (was 2), staging overlaps
//        compute.
//      - B keeps R2's [k][n] layout (reads along n are free 2-way).
//    Per-element k-accumulation order identical to R1-R5 (bit-stable).
#define BM 64
#define BN 64
#define BK 16
#define A_LD 20
#define B_LD 68
__global__ __launch_bounds__(256) void proj_gemm(
    const int* __restrict__ ids, const float* __restrict__ embed,
    const float* __restrict__ Wq, const float* __restrict__ Wk,
    float* __restrict__ C) {
  __shared__ float As[2][BM][A_LD];   // [m][k]+pad, 10240 B
  __shared__ float Bs[2][BK][B_LD];   // [k][n]+pad,  8704 B
  __shared__ int rowid[BM];
  const int t = threadIdx.x;           // 0..255
  const int col0 = blockIdx.x * BN;    // 40 col blocks
  const int row0 = blockIdx.y * BM;    // 32 row blocks
  const float* Wbase = (col0 < EQ) ? (Wq + (size_t)col0 * D)
                                   : (Wk + (size_t)(col0 - EQ) * D);
  if (t < BM) rowid[t] = ids[row0 + t];
  __syncthreads();

  // staging: A tile 64x16 = 256 quads -> thread owns (sm, sq); B same.
  const int sm = t >> 2;             // row 0..63
  const int sq = (t & 3) * 4;        // k quad offset 0,4,8,12
  const float* Arow = embed + (size_t)rowid[sm] * D + sq;
  const float* Brow = Wbase + (size_t)sm * D + sq;

  const int tm0 = (t >> 4) * 4;      // 4 s-rows
  const int tn0 = (t & 15) * 4;      // 4 e-cols
  float acc[4][4];
#pragma unroll
  for (int i = 0; i < 4; ++i)
#pragma unroll
    for (int j = 0; j < 4; ++j) acc[i][j] = 0.f;

  // stage k0 = 0 into buf 0
  {
    const float4 av = *(const float4*)(Arow);
    const float4 bv = *(const float4*)(Brow);
    *(float4*)&As[0][sm][sq] = av;
    Bs[0][sq + 0][sm] = bv.x; Bs[0][sq + 1][sm] = bv.y;
    Bs[0][sq + 2][sm] = bv.z; Bs[0][sq + 3][sm] = bv.w;
  }

  for (int k0 = 0; k0 < D; k0 += BK) {
    const int cur = (k0 >> 4) & 1;
    const int nxt = cur ^ 1;
    __syncthreads();   // cur-buf writes visible; prior nxt-buf reads retired
    const bool more = (k0 + BK) < D;
    float4 a_pf, b_pf;
    if (more) {
      a_pf = *(const float4*)(Arow + k0 + BK);
      b_pf = *(const float4*)(Brow + k0 + BK);
    }
#pragma unroll
    for (int g = 0; g < 4; ++g) {
      float4 a4[4];
#pragma unroll
      for (int i = 0; i < 4; ++i)
        a4[i] = *(const float4*)&As[cur][tm0 + i][g * 4];
#pragma unroll
      for (int kc = 0; kc < 4; ++kc) {
        const float4 bv = *(const float4*)&Bs[cur][g * 4 + kc][tn0];
        float a[4];
#pragma unroll
        for (int i = 0; i < 4; ++i)
          a[i] = (kc == 0) ? a4[i].x : (kc == 1) ? a4[i].y
               : (kc == 2) ? a4[i].z : a4[i].w;
#pragma unroll
        for (int i = 0; i < 4; ++i) {
          acc[i][0] = fmaf(a[i], bv.x, acc[i][0]);
          acc[i][1] = fmaf(a[i], bv.y, acc[i][1]);
          acc[i][2] = fmaf(a[i], bv.z, acc[i][2]);
          acc[i][3] = fmaf(a[i], bv.w, acc[i][3]);
        }
      }
    }
    if (more) {
      *(float4*)&As[nxt][sm][sq] = a_pf;
      Bs[nxt][sq + 0][sm] = b_pf.x; Bs[nxt][sq + 1][sm] = b_pf.y;
      Bs[nxt][sq + 2][sm] = b_pf.z; Bs[nxt][sq + 3][sm] = b_pf.w;
    }
  }
#pragma unroll
  for (int i = 0; i < 4; ++i) {
    float* dst = C + (size_t)(row0 + tm0 + i) * ETOT + col0 + tn0;
    *(float4*)dst = make_float4(acc[i][0], acc[i][1], acc[i][2], acc[i][3]);
  }
}

// ---------------------------------------------------------------------------
// 3) Fused RoPE: blocks [0, 8192) do q in place; blocks [8192, 8448) do k ->
//    transposed kT via LDS tile. Branch is block-uniform (no divergence).
//    Both paths bit-identical to R5's separate kernels.
__global__ __launch_bounds__(256) void rope_qk_kernel(
    float* __restrict__ qk, float* __restrict__ kT,
    const float* __restrict__ cosT, const float* __restrict__ sinT) {
  const int t = threadIdx.x;
  if (blockIdx.x < 8192) {
    int idx = blockIdx.x * 256 + t;     // S * NH * 32
    int s = idx >> 10;
    int rem = idx & 1023;
    int h = rem >> 5, i = rem & 31;
    float c = cosT[(s << 5) + i], sn = sinT[(s << 5) + i];
    float* p = qk + (size_t)s * ETOT + h * HD + i;
    float x1 = p[0], x2 = p[32];
    p[0]  = fmaf(x1, c, -x2 * sn);
    p[32] = fmaf(x2, c,  x1 * sn);
    return;
  }
  __shared__ float tile[64][65];
  __shared__ float ct[64][33];
  __shared__ float st[64][33];
  const int b = blockIdx.x - 8192;  // 0..255
  const int kv = b & 7;
  const int s0 = (b >> 3) * 64;
  {
    const int c = t & 63, r = t >> 6;
#pragma unroll
    for (int p = 0; p < 16; ++p)
      tile[r + 4 * p][c] = qk[(size_t)(s0 + r + 4 * p) * ETOT + EQ + kv * HD + c];
  }
  {
    const int i = t & 31, r = t >> 5;
#pragma unroll
    for (int p = 0; p < 8; ++p) {
      ct[r + 8 * p][i] = cosT[(s0 + r + 8 * p) * 32 + i];
      st[r + 8 * p][i] = sinT[(s0 + r + 8 * p) * 32 + i];
    }
  }
  __syncthreads();
  const int s = t & 63, dbase = t >> 6;
#pragma unroll
  for (int p = 0; p < 16; ++p) {
    const int d = dbase + 4 * p;
    float v;
    if (d < 32) {
      const float c = ct[s][d], sn = st[s][d];
      const float x1 = tile[s][d], x2 = tile[s][d + 32];
      v = fmaf(x1, c, -x2 * sn);
    } else {
      const float c = ct[s][d - 32], sn = st[s][d - 32];
      const float x1 = tile[s][d - 32], x2 = tile[s][d];
      v = fmaf(x2, c, x1 * sn);
    }
    kT[(size_t)(kv * HD + d) * S + s0 + s] = v;
  }
}

// ---------------------------------------------------------------------------
// 5) Attention. Unchanged from R5 (bit-identical); now that proj shrinks it
//    should surface in the top-5 profile for the next round's analysis.
__global__ __launch_bounds__(256) void attn_kernel(
    const float* __restrict__ qk, const float* __restrict__ kT,
    float* __restrict__ part) {
  const int h = blockIdx.x;    // 0..31
  const int sb = blockIdx.y;   // 0..31
  const int t = threadIdx.x;
  const float* kTh = kT + (size_t)(h >> 2) * HD * S;
  __shared__ float qlds[16][64];
  __shared__ float wred[4][16];
  float colacc[8];
#pragma unroll
  for (int u = 0; u < 8; ++u) colacc[u] = 0.f;
  const int c0 = t * 8;

  for (int ch = 0; ch < 4; ++ch) {
    const int row0 = sb * 64 + ch * 16;
    __syncthreads();
    {
      const int r = t >> 6, dd = t & 63;
#pragma unroll
      for (int rr = 0; rr < 4; ++rr)
        qlds[r + rr * 4][dd] = qk[(size_t)(row0 + r + rr * 4) * ETOT + h * HD + dd];
    }
    __syncthreads();
    float acc[16][8];
#pragma unroll
    for (int r = 0; r < 16; ++r)
#pragma unroll
      for (int u = 0; u < 8; ++u) acc[r][u] = 0.f;

    float4 c0a = *(const float4*)(kTh + c0);
    float4 c0b = *(const float4*)(kTh + c0 + 4);
    float4 c1a = *(const float4*)(kTh + (size_t)S + c0);
    float4 c1b = *(const float4*)(kTh + (size_t)S + c0 + 4);
    for (int d2 = 0; d2 < HD; d2 += 2) {
      const int dn = (d2 + 2) & (HD - 1);   // wrap; last prefetch discarded
      const float4 n0a = *(const float4*)(kTh + (size_t)dn * S + c0);
      const float4 n0b = *(const float4*)(kTh + (size_t)dn * S + c0 + 4);
      const float4 n1a = *(const float4*)(kTh + (size_t)(dn + 1) * S + c0);
      const float4 n1b = *(const float4*)(kTh + (size_t)(dn + 1) * S + c0 + 4);
      float2 q2[16];
#pragma unroll
      for (int r = 0; r < 16; ++r) q2[r] = *(const float2*)&qlds[r][d2];
      {
        const float kv[8] = {c0a.x, c0a.y, c0a.z, c0a.w, c0b.x, c0b.y, c0b.z, c0b.w};
#pragma unroll
        for (int r = 0; r < 16; ++r) {
          const float qd = q2[r].x;
#pragma unroll
          for (int u = 0; u < 8; ++u) acc[r][u] = fmaf(qd, kv[u], acc[r][u]);
        }
      }
      {
        const float kv[8] = {c1a.x, c1a.y, c1a.z, c1a.w, c1b.x, c1b.y, c1b.z, c1b.w};
#pragma unroll
        for (int r = 0; r < 16; ++r) {
          const float qd = q2[r].y;
#pragma unroll
          for (int u = 0; u < 8; ++u) acc[r][u] = fmaf(qd, kv[u], acc[r][u]);
        }
      }
      c0a = n0a; c0b = n0b; c1a = n1a; c1b = n1b;
    }
    float p[16];
#pragma unroll
    for (int r = 0; r < 16; ++r) {
      p[r] = 0.f;
#pragma unroll
      for (int u = 0; u < 8; ++u) {
        acc[r][u] = expf(acc[r][u]);
        p[r] += acc[r][u];
      }
    }
#pragma unroll
    for (int off = 32; off > 0; off >>= 1)
#pragma unroll
      for (int r = 0; r < 16; ++r) p[r] += __shfl_xor(p[r], off, 64);
    if ((t & 63) == 0) {
#pragma unroll
      for (int r = 0; r < 16; ++r) wred[t >> 6][r] = p[r];
    }
    __syncthreads();
#pragma unroll
    for (int r = 0; r < 16; ++r) {
      const float Z = wred[0][r] + wred[1][r] + wred[2][r] + wred[3][r];
      const float inv = 1.f / Z;
#pragma unroll
      for (int u = 0; u < 8; ++u) colacc[u] = fmaf(acc[r][u], inv, colacc[u]);
    }
  }
  const int b = h * 32 + sb;
  *(float4*)(part + (size_t)b * S + c0)     = make_float4(colacc[0], colacc[1], colacc[2], colacc[3]);
  *(float4*)(part + (size_t)b * S + c0 + 4) = make_float4(colacc[4], colacc[5], colacc[6], colacc[7]);
}

// ---------------------------------------------------------------------------
// 6) fp64 column totals, two stages (same left-to-right order as R3-R5).
__global__ void vals1_kernel(const float* __restrict__ part,
                             double* __restrict__ accp) {
  int j = blockIdx.x * 256 + threadIdx.x;  // 0..2047
  int g = blockIdx.y;                      // 0..31
  const float* p = part + (size_t)g * 32 * S + j;
  double s = 0.0;
  for (int b = 0; b < 32; ++b) s += (double)p[(size_t)b * S];
  accp[(size_t)g * S + j] = s;
}
__global__ void vals2_kernel(const double* __restrict__ accp,
                             double* __restrict__ vals) {
  int j = blockIdx.x * 256 + threadIdx.x;
  double s = 0.0;
  for (int g = 0; g < 32; ++g) s += accp[(size_t)g * S + j];
  vals[j] = s;
}

// 7) Exact rank, one block per j. Same predicate (tie-break: lower index
//    wins, matching lax.top_k); deterministic.
__global__ __launch_bounds__(256) void flags_kernel(
    const double* __restrict__ vals, int* __restrict__ flags) {
  const int j = blockIdx.x;       // 0..2047
  const int t = threadIdx.x;
  const double v = vals[j];
  int rank = 0;
  for (int j2 = t; j2 < S; j2 += 256) {
    const double v2 = vals[j2];
    rank += (v2 > v) || (v2 == v && j2 < j);
  }
#pragma unroll
  for (int off = 32; off > 0; off >>= 1) rank += __shfl_xor(rank, off, 64);
  __shared__ int red[4];
  if ((t & 63) == 0) red[t >> 6] = rank;
  __syncthreads();
  if (t == 0)
    flags[j] = ((red[0] + red[1] + red[2] + red[3]) < KLEN) ? 1 : 0;
}

// 8) Compact selected indices (ascending) + write tokens/indices + append S-1.
__global__ __launch_bounds__(1024) void emit_kernel(
    const int* __restrict__ flags, const int* __restrict__ ids,
    int* __restrict__ out) {
  __shared__ int fl[S];
  __shared__ int csum[32];
  __shared__ int cpre[32];
  const int t = threadIdx.x;
  for (int j = t; j < S; j += 1024) fl[j] = flags[j];
  __syncthreads();
  if (t < 32) {
    int s = 0;
    for (int i = 0; i < 64; ++i) s += fl[t * 64 + i];
    csum[t] = s;
  }
  __syncthreads();
  if (t == 0) {
    int run = 0;
    for (int c = 0; c < 32; ++c) { cpre[c] = run; run += csum[c]; }
  }
  __syncthreads();
  for (int j = t; j < S; j += 1024) {
    if (fl[j]) {
      int pos = cpre[j >> 6];
      for (int j2 = j & ~63; j2 < j; ++j2) pos += fl[j2];
      out[pos] = ids[j];            // pruned tokens [0..1023]
      out[KLEN + 1 + pos] = j;      // indices [1025..2048]
    }
  }
  if (t == 0) {
    out[KLEN] = ids[S - 1];
    out[KLEN + 1 + KLEN] = S - 1;
  }
}

// ---------------------------------------------------------------------------
extern "C" void kernel_launch(void* const* d_in, const int* in_sizes, int n_in,
                              void* d_out, int out_size, void* d_ws, size_t ws_size,
                              hipStream_t stream) {
  const int* ids = (const int*)d_in[0];
  const float* embed = (const float*)d_in[1];
  const float* Wq = (const float*)d_in[2];
  const float* Wk = (const float*)d_in[3];
  int* out = (int*)d_out;
  char* ws = (char*)d_ws;
  float* cosT = (float*)(ws + OFF_COS);
  float* sinT = (float*)(ws + OFF_SIN);
  float* qk   = (float*)(ws + OFF_QK);
  float* kT   = (float*)(ws + OFF_KT);
  float* part = (float*)(ws + OFF_PART);
  double* vals = (double*)(ws + OFF_VALS);
  int* flags  = (int*)(ws + OFF_FLAGS);
  double* accp = (double*)(ws + OFF_ACCP);

  trig_kernel<<<256, 256, 0, stream>>>(cosT, sinT);
  proj_gemm<<<dim3(ETOT / BN, S / BM), 256, 0, stream>>>(ids, embed, Wq, Wk, qk);
  rope_qk_kernel<<<8192 + 256, 256, 0, stream>>>(qk, kT, cosT, sinT);
  attn_kernel<<<dim3(NH, 32), 256, 0, stream>>>(qk, kT, part);
  vals1_kernel<<<dim3(S / 256, 32), 256, 0, stream>>>(part, accp);
  vals2_kernel<<<S / 256, 256, 0, stream>>>(accp, vals);
  flags_kernel<<<S, 256, 0, stream>>>(vals, flags);
  emit_kernel<<<1, 1024, 0, stream>>>(flags, ids, out);
}